// Round 13
// baseline (1205.791 us; speedup 1.0000x reference)
//
#include <hip/hip_runtime.h>
#include <math.h>

#ifndef M_PI
#define M_PI 3.14159265358979323846
#endif

typedef __attribute__((ext_vector_type(8))) __bf16 bf16x8;
typedef __attribute__((ext_vector_type(4))) float f32x4;
typedef __attribute__((ext_vector_type(2))) float f32x2;
typedef __attribute__((ext_vector_type(8))) unsigned short ushort8;
typedef __attribute__((ext_vector_type(4))) unsigned short ushort4v;

__device__ __forceinline__ unsigned short f2bf(float x) {
    unsigned int u = __float_as_uint(x);
    unsigned int r = (u + 0x7FFFu + ((u >> 16) & 1u)) >> 16;
    return (unsigned short)r;
}

// packed f32 FMA: two independent IEEE fmaf lanes per instruction.
// src0's op_sel broadcasts ONE scalar (lo or hi of the pair) to both lanes:
// PKFMA_L: d = { fma(a.x,b.x,d.x), fma(a.x,b.y,d.y) }
// PKFMA_H: d = { fma(a.y,b.x,d.x), fma(a.y,b.y,d.y) }
#define PKFMA_L(d, a, b) \
    asm("v_pk_fma_f32 %0, %1, %2, %0 op_sel:[0,0,0] op_sel_hi:[0,1,1]" \
        : "+v"(d) : "v"(a), "v"(b))
#define PKFMA_H(d, a, b) \
    asm("v_pk_fma_f32 %0, %1, %2, %0 op_sel:[1,0,0] op_sel_hi:[1,1,1]" \
        : "+v"(d) : "v"(a), "v"(b))

// ---------------------------------------------------------------------------
// numpy-exact row norms of keys (4096 x 2048), 16 rows/block, 16 thr/row.
// den[r] = nrm + 1e-8f (decision path), vnorm[r] = nrm (continuous colscale)
// ---------------------------------------------------------------------------
__global__ __launch_bounds__(256)
void norm_np_k(const float* __restrict__ keys,
               float* __restrict__ den,
               float* __restrict__ vnorm)
{
#pragma clang fp contract(off)
    const int tid = threadIdx.x;
    const int row_l = tid >> 4;
    const int blk = tid & 15;
    const int row = blockIdx.x * 16 + row_l;
    const float* a = keys + (size_t)row * 2048 + blk * 128;

    float r0 = a[0]*a[0], r1 = a[1]*a[1], r2 = a[2]*a[2], r3 = a[3]*a[3];
    float r4 = a[4]*a[4], r5 = a[5]*a[5], r6 = a[6]*a[6], r7 = a[7]*a[7];
    for (int i = 8; i < 128; i += 8) {
        r0 += a[i+0]*a[i+0]; r1 += a[i+1]*a[i+1];
        r2 += a[i+2]*a[i+2]; r3 += a[i+3]*a[i+3];
        r4 += a[i+4]*a[i+4]; r5 += a[i+5]*a[i+5];
        r6 += a[i+6]*a[i+6]; r7 += a[i+7]*a[i+7];
    }
    float bsum = ((r0 + r1) + (r2 + r3)) + ((r4 + r5) + (r6 + r7));

    __shared__ float bs[16][16];
    bs[row_l][blk] = bsum;
    __syncthreads();
    if (blk == 0) {
        const float* b = bs[row_l];
        float q0 = ((b[0] + b[1]) + (b[2] + b[3])) + ((b[4] + b[5]) + (b[6] + b[7]));
        float q1 = ((b[8] + b[9]) + (b[10] + b[11])) + ((b[12] + b[13]) + (b[14] + b[15]));
        float s = q0 + q1;
        float n = (float)sqrt((double)s);
        den[row] = n + 1e-8f;
        vnorm[row] = n;
    }
}

// ---------------------------------------------------------------------------
// kn[r,d] = keys[r,d] / den[r]  (correctly-rounded f32 div; decision-exact)
// ---------------------------------------------------------------------------
__global__ __launch_bounds__(256)
void kn_k(const float* __restrict__ keys,
          const float* __restrict__ den,
          float* __restrict__ kn)
{
#pragma clang fp contract(off)
    const int idx = (blockIdx.x * 256 + threadIdx.x) * 8;
    const int row = idx >> 11;
    const float d = den[row];
    float4 v0 = *(const float4*)(keys + idx);
    float4 v1 = *(const float4*)(keys + idx + 4);
    v0.x /= d; v0.y /= d; v0.z /= d; v0.w /= d;
    v1.x /= d; v1.y /= d; v1.z /= d; v1.w /= d;
    *(float4*)(kn + idx) = v0;
    *(float4*)(kn + idx + 4) = v1;
}

// ---------------------------------------------------------------------------
// f32 -> bf16 (RNE), 8 elements/thread.
// ---------------------------------------------------------------------------
__global__ __launch_bounds__(256)
void f2bf_k(const float* __restrict__ in, unsigned short* __restrict__ out)
{
    const int i = (blockIdx.x * 256 + threadIdx.x) * 8;
    float4 v0 = *(const float4*)(in + i);
    float4 v1 = *(const float4*)(in + i + 4);
    ushort8 o;
    o[0] = f2bf(v0.x); o[1] = f2bf(v0.y); o[2] = f2bf(v0.z); o[3] = f2bf(v0.w);
    o[4] = f2bf(v1.x); o[5] = f2bf(v1.y); o[6] = f2bf(v1.z); o[7] = f2bf(v1.w);
    *(ushort8*)(out + i) = o;
}

// ---------------------------------------------------------------------------
// Decision-path f32 GEMM (bitwise numpy-f32 chain): C = A(MxK) @ B(NxK)^T.
// Per output element: ONE sequential fmaf chain over k (order preserved:
// panel -> group g -> j ascending).
//
// r13 design (r11 model: LDS-instr bound, busy = VALU/LDScyc): per-thread
// tile 16 rows x 8 cols (block tile 256x128). Per 4-kk group: A = 16 b128
// ([row][k] layout, {k0..k3} in one read -> f32x2 op_sel pairs, zero movs),
// B = 8 b128 ([k][col]) -> 6 b128/kk for 64 pk_fma vs r11's 4/kk for 32.
// Predicted VALU busy cap ~89% (vs 66.7% measured on 8x8).
// A pad 21: rows {0,4,8,12}*21 distinct banks; rows 64 apart are in
// different instructions. Coalesced staging: 16 rows x 64B per instr.
//   EPI 0: Cf[r,c] = total (f32)
//   EPI 1: Cb[r,c] = bf16( sign(total) * rv[r] )
// blockIdx.z selects (A+z*a_zoff, B0/B1, rv0/rv1, Cb+z*c_zoff).
// ---------------------------------------------------------------------------
template <int EPI>
__global__ __launch_bounds__(256, 2)
void gemm_dec_k(const float* __restrict__ A, int lda, int a_zoff,
                const float* __restrict__ B0, const float* __restrict__ B1,
                int ldb,
                float* __restrict__ Cf, unsigned short* __restrict__ Cb,
                int c_zoff, int ldc, int K,
                const float* __restrict__ rv0, const float* __restrict__ rv1)
{
#pragma clang fp contract(off)
    __shared__ float As[2][256][21];   // [buf][row][k], pad 5
    __shared__ float Bs[2][16][132];   // [buf][k][col], pad 4

    const int z = blockIdx.z;
    const float* Ap = A + (size_t)z * a_zoff;
    const float* Bp = z ? B1 : B0;
    const float* rvp = z ? rv1 : rv0;
    unsigned short* Cbp = (EPI == 1) ? (Cb + (size_t)z * c_zoff) : nullptr;

    const int tid = threadIdx.x;
    const int tr = tid >> 4;            // 0..15 (row group)
    const int tc4 = (tid & 15) * 4;     // col offset
    const int row0 = blockIdx.y * 256;
    const int col0 = blockIdx.x * 128;

    // staging geometry
    const int arow = tid >> 2;          // 0..63
    const int akf  = (tid & 3) * 4;     // 0,4,8,12
    const int bcol = tid >> 1;          // 0..127
    const int bk   = (tid & 1) * 8;     // 0,8

    const float* gb = Bp + (size_t)(col0 + bcol) * ldb + bk;

    f32x2 acc[16][4] = {};   // [r = m*4+i][col-pair q]
    float4 sa[4];
    float4 sbv0, sbv1;

#define LOADSTAGE(koff) do { \
    _Pragma("unroll") \
    for (int j4 = 0; j4 < 4; ++j4) \
        sa[j4] = *(const float4*)(Ap + (size_t)(row0 + arow + j4 * 64) * lda + (koff) + akf); \
    sbv0 = *(const float4*)(gb + (koff)); \
    sbv1 = *(const float4*)(gb + (koff) + 4); \
} while (0)

#define STORESTAGE(buf) do { \
    _Pragma("unroll") \
    for (int j4 = 0; j4 < 4; ++j4) \
        *(float4*)&As[buf][arow + j4 * 64][akf] = sa[j4]; \
    Bs[buf][bk + 0][bcol] = sbv0.x; Bs[buf][bk + 1][bcol] = sbv0.y; \
    Bs[buf][bk + 2][bcol] = sbv0.z; Bs[buf][bk + 3][bcol] = sbv0.w; \
    Bs[buf][bk + 4][bcol] = sbv1.x; Bs[buf][bk + 5][bcol] = sbv1.y; \
    Bs[buf][bk + 6][bcol] = sbv1.z; Bs[buf][bk + 7][bcol] = sbv1.w; \
} while (0)

    LOADSTAGE(0);
    STORESTAGE(0);
    __syncthreads();
    int cur = 0;

    for (int k0 = 0; k0 < K; k0 += 16) {
        const bool more = (k0 + 16 < K);
        if (more) LOADSTAGE(k0 + 16);

        #pragma unroll
        for (int g = 0; g < 4; ++g) {
            // B fragments for the 4 kks of this group
            f32x2 fb[4][4];
            #pragma unroll
            for (int j = 0; j < 4; ++j) {
                float4 vb0 = *(const float4*)&Bs[cur][g * 4 + j][tc4];
                float4 vb1 = *(const float4*)&Bs[cur][g * 4 + j][tc4 + 64];
                fb[j][0] = (f32x2){vb0.x, vb0.y};
                fb[j][1] = (f32x2){vb0.z, vb0.w};
                fb[j][2] = (f32x2){vb1.x, vb1.y};
                fb[j][3] = (f32x2){vb1.z, vb1.w};
            }
            // A per row: one b128 = {k0,k1,k2,k3}; sequential j over k
            #pragma unroll
            for (int m = 0; m < 4; ++m) {
                #pragma unroll
                for (int i = 0; i < 4; ++i) {
                    float4 a4 = *(const float4*)&As[cur][m * 64 + tr * 4 + i][g * 4];
                    f32x2 a01 = (f32x2){a4.x, a4.y};
                    f32x2 a23 = (f32x2){a4.z, a4.w};
                    const int r = m * 4 + i;
                    #pragma unroll
                    for (int q = 0; q < 4; ++q) PKFMA_L(acc[r][q], a01, fb[0][q]);
                    #pragma unroll
                    for (int q = 0; q < 4; ++q) PKFMA_H(acc[r][q], a01, fb[1][q]);
                    #pragma unroll
                    for (int q = 0; q < 4; ++q) PKFMA_L(acc[r][q], a23, fb[2][q]);
                    #pragma unroll
                    for (int q = 0; q < 4; ++q) PKFMA_H(acc[r][q], a23, fb[3][q]);
                }
            }
        }

        if (more) STORESTAGE(cur ^ 1);
        __syncthreads();
        cur ^= 1;
    }

    #pragma unroll
    for (int r = 0; r < 16; ++r) {
        const int row = row0 + (r >> 2) * 64 + tr * 4 + (r & 3);
        if (EPI == 0) {
            float4 lo4 = {acc[r][0].x, acc[r][0].y, acc[r][1].x, acc[r][1].y};
            float4 hi4 = {acc[r][2].x, acc[r][2].y, acc[r][3].x, acc[r][3].y};
            *(float4*)&Cf[(size_t)row * ldc + col0 + tc4]      = lo4;
            *(float4*)&Cf[(size_t)row * ldc + col0 + 64 + tc4] = hi4;
        } else {
            const float s = rvp[row];
            float v[8] = {acc[r][0].x, acc[r][0].y, acc[r][1].x, acc[r][1].y,
                          acc[r][2].x, acc[r][2].y, acc[r][3].x, acc[r][3].y};
            ushort4v o0, o1;
            #pragma unroll
            for (int j = 0; j < 4; ++j) {
                const float t0 = v[j];
                o0[j] = f2bf((t0 > 0.0f) ? s : ((t0 < 0.0f) ? -s : 0.0f));
                const float t1 = v[4 + j];
                o1[j] = f2bf((t1 > 0.0f) ? s : ((t1 < 0.0f) ? -s : 0.0f));
            }
            *(ushort4v*)&Cbp[(size_t)row * ldc + col0 + tc4]      = o0;
            *(ushort4v*)&Cbp[(size_t)row * ldc + col0 + 64 + tc4] = o1;
        }
    }
#undef LOADSTAGE
#undef STORESTAGE
}

// ---------------------------------------------------------------------------
// Quantize one key row (f32, numpy-exact decisions): nearest centroid
// (first-min ties), residual in place over Y, bf16 y_mse into Bbig[:,0:2048],
// sc = coef * ||res_group||  (continuous; vnorm applied in final colscale).
// ---------------------------------------------------------------------------
__global__ __launch_bounds__(256)
void quant_k(float* __restrict__ Y,
             unsigned short* __restrict__ Bmse,   // ld 4096
             const float* __restrict__ ch,
             const float* __restrict__ cl,
             float* __restrict__ sc_h,
             float* __restrict__ sc_l,
             double coefd)
{
#pragma clang fp contract(off)
    const int row = blockIdx.x;
    const int tid = threadIdx.x;
    const int c0 = tid * 8;
    const float h0 = ch[0], h1 = ch[1], h2 = ch[2], h3 = ch[3];
    const float l0 = cl[0], l1 = cl[1];

    float y[8], res[8];
    ushort8 cb;
    *(float4*)(y)     = *(const float4*)(Y + (size_t)row * 2048 + c0);
    *(float4*)(y + 4) = *(const float4*)(Y + (size_t)row * 2048 + c0 + 4);

    const bool high = (tid < 128);
    float ss = 0.0f;
    #pragma unroll
    for (int j = 0; j < 8; ++j) {
        const float v = y[j];
        float cbest;
        if (high) {
            cbest = h0;
            float bd = fabsf(v - h0), dd;
            dd = fabsf(v - h1); if (dd < bd) { bd = dd; cbest = h1; }
            dd = fabsf(v - h2); if (dd < bd) { bd = dd; cbest = h2; }
            dd = fabsf(v - h3); if (dd < bd) { bd = dd; cbest = h3; }
        } else {
            cbest = (fabsf(v - l1) < fabsf(v - l0)) ? l1 : l0;
        }
        res[j] = v - cbest;
        cb[j] = f2bf(cbest);
        ss += res[j] * res[j];
    }
    *(float4*)(Y + (size_t)row * 2048 + c0)     = *(float4*)(res);
    *(float4*)(Y + (size_t)row * 2048 + c0 + 4) = *(float4*)(res + 4);
    *(ushort8*)(Bmse + (size_t)row * 4096 + c0) = cb;

    __shared__ float sm[256];
    sm[tid] = ss;
    __syncthreads();
    for (int o = 64; o > 0; o >>= 1) {
        if ((tid & 127) < o) sm[tid] += sm[tid + o];
        __syncthreads();
    }
    if (tid == 0)   sc_h[row] = (float)(coefd * sqrt((double)sm[0]));
    if (tid == 128) sc_l[row] = (float)(coefd * sqrt((double)sm[128]));
}

// ---------------------------------------------------------------------------
// Continuous-path bf16 MFMA GEMM: C = A(MxK bf16) @ B(NxK bf16)^T, f32 accum.
// 128x128 tile, 4 waves (2x2), 4x4 16x16x32 fragments per wave.
// blockIdx.z selects (A+z*a_zoff, B0/B1, Cb+z*c_zoff).
//   EPI 1: Cf[r,c] = acc * colscale[c]
//   EPI 2: Cb[r,c] = bf16(acc)
// ---------------------------------------------------------------------------
template <int EPI>
__global__ __launch_bounds__(256)
void gemm_mfma_k(const unsigned short* __restrict__ A, int lda, int a_zoff,
                 const unsigned short* __restrict__ B0,
                 const unsigned short* __restrict__ B1, int ldb,
                 float* __restrict__ Cf, unsigned short* __restrict__ Cb,
                 int c_zoff, int ldc, int K,
                 const float* __restrict__ colscale)
{
    __shared__ unsigned short As[128][40];
    __shared__ unsigned short Bs[128][40];

    const int z = blockIdx.z;
    const unsigned short* Ap = A + (size_t)z * a_zoff;
    const unsigned short* Bp = z ? B1 : B0;
    unsigned short* Cbp = (EPI == 2) ? (Cb + (size_t)z * c_zoff) : nullptr;

    const int tid = threadIdx.x;
    const int lane = tid & 63;
    const int wid = tid >> 6;
    const int wm = wid >> 1;
    const int wn = wid & 1;
    const int row0 = blockIdx.y * 128;
    const int col0 = blockIdx.x * 128;
    const int sr = tid >> 1;
    const int sk = (tid & 1) * 16;
    const int frow = lane & 15;
    const int fk = (lane >> 4) * 8;

    const unsigned short* ga = Ap + (size_t)(row0 + sr) * lda + sk;
    const unsigned short* gb = Bp + (size_t)(col0 + sr) * ldb + sk;

    f32x4 acc[4][4] = {};

    for (int k0 = 0; k0 < K; k0 += 32) {
        ushort8 a0 = *(const ushort8*)(ga + k0);
        ushort8 a1 = *(const ushort8*)(ga + k0 + 8);
        ushort8 b0 = *(const ushort8*)(gb + k0);
        ushort8 b1 = *(const ushort8*)(gb + k0 + 8);
        __syncthreads();
        *(ushort8*)&As[sr][sk]     = a0;
        *(ushort8*)&As[sr][sk + 8] = a1;
        *(ushort8*)&Bs[sr][sk]     = b0;
        *(ushort8*)&Bs[sr][sk + 8] = b1;
        __syncthreads();

        bf16x8 af[4], bfr[4];
        #pragma unroll
        for (int mi = 0; mi < 4; ++mi)
            af[mi] = *(const bf16x8*)&As[wm * 64 + mi * 16 + frow][fk];
        #pragma unroll
        for (int ni = 0; ni < 4; ++ni)
            bfr[ni] = *(const bf16x8*)&Bs[wn * 64 + ni * 16 + frow][fk];
        #pragma unroll
        for (int mi = 0; mi < 4; ++mi)
            #pragma unroll
            for (int ni = 0; ni < 4; ++ni)
                acc[mi][ni] = __builtin_amdgcn_mfma_f32_16x16x32_bf16(
                    af[mi], bfr[ni], acc[mi][ni], 0, 0, 0);
    }

    const int drow = (lane >> 4) * 4;
    const int dcol = lane & 15;
    #pragma unroll
    for (int mi = 0; mi < 4; ++mi) {
        #pragma unroll
        for (int ni = 0; ni < 4; ++ni) {
            const int c = col0 + wn * 64 + ni * 16 + dcol;
            const float cs = (EPI == 1) ? colscale[c] : 0.0f;
            #pragma unroll
            for (int rg = 0; rg < 4; ++rg) {
                const int r = row0 + wm * 64 + mi * 16 + drow + rg;
                const float v = acc[mi][ni][rg];
                if (EPI == 1) Cf[(size_t)r * ldc + c] = v * cs;
                else          Cbp[(size_t)r * ldc + c] = f2bf(v);
            }
        }
    }
}

// ---------------------------------------------------------------------------
// Launch. Workspace (~120.1 MB):
//   kn    @   0M : 4096x2048 f32
//   Y     @  32M : 4096x2048 f32 (y, then residual in place)
//   Bbig  @  64M : 4096x4096 bf16  [ymse | sgn*sc_h | sgn*sc_l]
//   Abig  @  96M : 1024x4096 bf16  [q_rot | z_h | z_l]
//   Qb    @ 104M, Pib @ 108M, Sbh @ 116M, Sbl @ 118M : bf16 inputs
//   den   @ 120M, vnorm +16K, sc_h +32K, sc_l +48K
// ---------------------------------------------------------------------------
extern "C" void kernel_launch(void* const* d_in, const int* in_sizes, int n_in,
                              void* d_out, int out_size, void* d_ws, size_t ws_size,
                              hipStream_t stream)
{
    const float* queries = (const float*)d_in[0];
    const float* keys    = (const float*)d_in[1];
    const float* Pi      = (const float*)d_in[2];
    const float* ch      = (const float*)d_in[3];
    const float* cl      = (const float*)d_in[4];
    const float* S_high  = (const float*)d_in[5];
    const float* S_low   = (const float*)d_in[6];
    float* out = (float*)d_out;

    char* ws = (char*)d_ws;
    float*          kn    = (float*)(ws);
    float*          Y     = (float*)(ws + ((size_t)32 << 20));
    unsigned short* Bbig  = (unsigned short*)(ws + ((size_t)64 << 20));
    unsigned short* Abig  = (unsigned short*)(ws + ((size_t)96 << 20));
    unsigned short* Qb    = (unsigned short*)(ws + ((size_t)104 << 20));
    unsigned short* Pib   = (unsigned short*)(ws + ((size_t)108 << 20));
    unsigned short* Sbh   = (unsigned short*)(ws + ((size_t)116 << 20));
    unsigned short* Sbl   = (unsigned short*)(ws + ((size_t)118 << 20));
    float*          den   = (float*)(ws + ((size_t)120 << 20));
    float*          vnorm = (float*)(ws + ((size_t)120 << 20) + 16384);
    float*          sc_h  = (float*)(ws + ((size_t)120 << 20) + 32768);
    float*          sc_l  = (float*)(ws + ((size_t)120 << 20) + 49152);

    const double coefd = sqrt(M_PI / 2.0) / 1024.0;

    // numpy-exact norms
    norm_np_k<<<256, 256, 0, stream>>>(keys, den, vnorm);

    // decision-exact normalized keys
    kn_k<<<4096, 256, 0, stream>>>(keys, den, kn);

    // bf16 copies for the continuous MFMA path
    f2bf_k<<<1024, 256, 0, stream>>>(queries, Qb);
    f2bf_k<<<2048, 256, 0, stream>>>(Pi, Pib);
    f2bf_k<<<512, 256, 0, stream>>>(S_high, Sbh);
    f2bf_k<<<512, 256, 0, stream>>>(S_low, Sbl);

    // DECISION: Y = kn @ Pi^T  (f32 exact sequential chain, 16x8 tile)
    gemm_dec_k<0><<<dim3(16, 16, 1), 256, 0, stream>>>(
        kn, 2048, 0, Pi, Pi, 2048, Y, nullptr, 0, 2048, 2048, nullptr, nullptr);

    // DECISION: quantize -> residual in Y, bf16 ymse in Bbig, sc_h/sc_l
    quant_k<<<4096, 256, 0, stream>>>(Y, Bbig, ch, cl, sc_h, sc_l, coefd);

    // DECISION: scaled signs (z=0: high, z=1: low) -> bf16 into Bbig cols 2048+
    gemm_dec_k<1><<<dim3(8, 16, 2), 256, 0, stream>>>(
        Y, 2048, 1024, S_high, S_low, 1024,
        nullptr, Bbig + 2048, 1024, 4096, 1024, sc_h, sc_l);

    // CONTINUOUS (bf16 MFMA): Abig = [q_rot | z_h | z_l]
    gemm_mfma_k<2><<<dim3(16, 8, 1), 256, 0, stream>>>(
        Qb, 2048, 0, Pib, Pib, 2048, nullptr, Abig, 0, 4096, 2048, nullptr);
    gemm_mfma_k<2><<<dim3(8, 8, 2), 256, 0, stream>>>(
        Abig, 4096, 1024, Sbh, Sbl, 1024, nullptr, Abig + 2048, 1024, 4096, 1024, nullptr);

    // CONTINUOUS: out = (Abig @ Bbig^T) * vnorm[col]   (K=4096 fused)
    gemm_mfma_k<1><<<dim3(32, 8, 1), 256, 0, stream>>>(
        Abig, 4096, 0, Bbig, Bbig, 4096, out, nullptr, 0, 4096, 4096, vnorm);
}

// Round 14
// 776.772 us; speedup vs baseline: 1.5523x; 1.5523x over previous
//
#include <hip/hip_runtime.h>
#include <math.h>

#ifndef M_PI
#define M_PI 3.14159265358979323846
#endif

typedef __attribute__((ext_vector_type(8))) __bf16 bf16x8;
typedef __attribute__((ext_vector_type(4))) float f32x4;
typedef __attribute__((ext_vector_type(2))) float f32x2;
typedef __attribute__((ext_vector_type(8))) unsigned short ushort8;
typedef __attribute__((ext_vector_type(4))) unsigned short ushort4v;

__device__ __forceinline__ unsigned short f2bf(float x) {
    unsigned int u = __float_as_uint(x);
    unsigned int r = (u + 0x7FFFu + ((u >> 16) & 1u)) >> 16;
    return (unsigned short)r;
}

// packed f32 FMA: two independent IEEE fmaf lanes per instruction.
// PKFMA_L: d = { fma(a.x,b.x,d.x), fma(a.x,b.y,d.y) }   (broadcast a.lo)
// PKFMA_H: d = { fma(a.y,b.x,d.x), fma(a.y,b.y,d.y) }   (broadcast a.hi)
#define PKFMA_L(d, a, b) \
    asm("v_pk_fma_f32 %0, %1, %2, %0 op_sel:[0,0,0] op_sel_hi:[0,1,1]" \
        : "+v"(d) : "v"(a), "v"(b))
#define PKFMA_H(d, a, b) \
    asm("v_pk_fma_f32 %0, %1, %2, %0 op_sel:[1,0,0] op_sel_hi:[1,1,1]" \
        : "+v"(d) : "v"(a), "v"(b))

// ---------------------------------------------------------------------------
// numpy-exact row norms of keys (4096 x 2048), 16 rows/block, 16 thr/row.
// den[r] = nrm + 1e-8f (decision path), vnorm[r] = nrm (continuous colscale)
// ---------------------------------------------------------------------------
__global__ __launch_bounds__(256)
void norm_np_k(const float* __restrict__ keys,
               float* __restrict__ den,
               float* __restrict__ vnorm)
{
#pragma clang fp contract(off)
    const int tid = threadIdx.x;
    const int row_l = tid >> 4;
    const int blk = tid & 15;
    const int row = blockIdx.x * 16 + row_l;
    const float* a = keys + (size_t)row * 2048 + blk * 128;

    float r0 = a[0]*a[0], r1 = a[1]*a[1], r2 = a[2]*a[2], r3 = a[3]*a[3];
    float r4 = a[4]*a[4], r5 = a[5]*a[5], r6 = a[6]*a[6], r7 = a[7]*a[7];
    for (int i = 8; i < 128; i += 8) {
        r0 += a[i+0]*a[i+0]; r1 += a[i+1]*a[i+1];
        r2 += a[i+2]*a[i+2]; r3 += a[i+3]*a[i+3];
        r4 += a[i+4]*a[i+4]; r5 += a[i+5]*a[i+5];
        r6 += a[i+6]*a[i+6]; r7 += a[i+7]*a[i+7];
    }
    float bsum = ((r0 + r1) + (r2 + r3)) + ((r4 + r5) + (r6 + r7));

    __shared__ float bs[16][16];
    bs[row_l][blk] = bsum;
    __syncthreads();
    if (blk == 0) {
        const float* b = bs[row_l];
        float q0 = ((b[0] + b[1]) + (b[2] + b[3])) + ((b[4] + b[5]) + (b[6] + b[7]));
        float q1 = ((b[8] + b[9]) + (b[10] + b[11])) + ((b[12] + b[13]) + (b[14] + b[15]));
        float s = q0 + q1;
        float n = (float)sqrt((double)s);
        den[row] = n + 1e-8f;
        vnorm[row] = n;
    }
}

// ---------------------------------------------------------------------------
// kn[r,d] = keys[r,d] / den[r]  (correctly-rounded f32 div; decision-exact)
// ---------------------------------------------------------------------------
__global__ __launch_bounds__(256)
void kn_k(const float* __restrict__ keys,
          const float* __restrict__ den,
          float* __restrict__ kn)
{
#pragma clang fp contract(off)
    const int idx = (blockIdx.x * 256 + threadIdx.x) * 8;
    const int row = idx >> 11;
    const float d = den[row];
    float4 v0 = *(const float4*)(keys + idx);
    float4 v1 = *(const float4*)(keys + idx + 4);
    v0.x /= d; v0.y /= d; v0.z /= d; v0.w /= d;
    v1.x /= d; v1.y /= d; v1.z /= d; v1.w /= d;
    *(float4*)(kn + idx) = v0;
    *(float4*)(kn + idx + 4) = v1;
}

// ---------------------------------------------------------------------------
// f32 -> bf16 (RNE), 8 elements/thread.
// ---------------------------------------------------------------------------
__global__ __launch_bounds__(256)
void f2bf_k(const float* __restrict__ in, unsigned short* __restrict__ out)
{
    const int i = (blockIdx.x * 256 + threadIdx.x) * 8;
    float4 v0 = *(const float4*)(in + i);
    float4 v1 = *(const float4*)(in + i + 4);
    ushort8 o;
    o[0] = f2bf(v0.x); o[1] = f2bf(v0.y); o[2] = f2bf(v0.z); o[3] = f2bf(v0.w);
    o[4] = f2bf(v1.x); o[5] = f2bf(v1.y); o[6] = f2bf(v1.z); o[7] = f2bf(v1.w);
    *(ushort8*)(out + i) = o;
}

// ---------------------------------------------------------------------------
// Decision-path f32 GEMM (bitwise numpy-f32 chain): C = A(MxK) @ B(NxK)^T.
// r11-proven config: 128x128 tile, 8x8/thread, [k][*] transposed LDS
// (conflict-cheap), LDS double-buffered, pk_fma with op_sel broadcast.
// Per output element: ONE sequential fmaf chain over k (order unchanged).
//   EPI 0: Cf[r,c] = total (f32)
//   EPI 1: Cb[r,c] = bf16( sign(total) * rv[r] )
// blockIdx.z selects (A+z*a_zoff, B0/B1, rv0/rv1, Cb+z*c_zoff).
// ---------------------------------------------------------------------------
template <int EPI>
__global__ __launch_bounds__(256, 2)
void gemm_dec_k(const float* __restrict__ A, int lda, int a_zoff,
                const float* __restrict__ B0, const float* __restrict__ B1,
                int ldb,
                float* __restrict__ Cf, unsigned short* __restrict__ Cb,
                int c_zoff, int ldc, int K,
                const float* __restrict__ rv0, const float* __restrict__ rv1)
{
#pragma clang fp contract(off)
    __shared__ float As[2][16][132];
    __shared__ float Bs[2][16][132];

    const int z = blockIdx.z;
    const float* Ap = A + (size_t)z * a_zoff;
    const float* Bp = z ? B1 : B0;
    const float* rvp = z ? rv1 : rv0;
    unsigned short* Cbp = (EPI == 1) ? (Cb + (size_t)z * c_zoff) : nullptr;

    const int tid = threadIdx.x;
    const int tr4 = (tid >> 4) * 4;
    const int tc4 = (tid & 15) * 4;
    const int row0 = blockIdx.y * 128;
    const int col0 = blockIdx.x * 128;
    const int sr = tid >> 1;
    const int sk = (tid & 1) * 8;

    const float* ga = Ap + (size_t)(row0 + sr) * lda + sk;
    const float* gb = Bp + (size_t)(col0 + sr) * ldb + sk;

    f32x2 acc[8][4] = {};
    float sa[8], sb[8];

#define LOADSTAGE(off) do { \
    *(float4*)(sa)     = *(const float4*)(ga + (off)); \
    *(float4*)(sa + 4) = *(const float4*)(ga + (off) + 4); \
    *(float4*)(sb)     = *(const float4*)(gb + (off)); \
    *(float4*)(sb + 4) = *(const float4*)(gb + (off) + 4); \
} while (0)

#define STORESTAGE(buf) do { \
    _Pragma("unroll") \
    for (int u = 0; u < 8; ++u) { \
        As[buf][sk + u][sr] = sa[u]; \
        Bs[buf][sk + u][sr] = sb[u]; \
    } \
} while (0)

#define RDFRAG(fa, fb, kk, buf) do { \
    float4 va0 = *(const float4*)&As[buf][kk][tr4]; \
    float4 va1 = *(const float4*)&As[buf][kk][tr4 + 64]; \
    float4 vb0 = *(const float4*)&Bs[buf][kk][tc4]; \
    float4 vb1 = *(const float4*)&Bs[buf][kk][tc4 + 64]; \
    (fa)[0] = (f32x2){va0.x, va0.y}; (fa)[1] = (f32x2){va0.z, va0.w}; \
    (fa)[2] = (f32x2){va1.x, va1.y}; (fa)[3] = (f32x2){va1.z, va1.w}; \
    (fb)[0] = (f32x2){vb0.x, vb0.y}; (fb)[1] = (f32x2){vb0.z, vb0.w}; \
    (fb)[2] = (f32x2){vb1.x, vb1.y}; (fb)[3] = (f32x2){vb1.z, vb1.w}; \
} while (0)

#define FMAS(fa, fb) do { \
    _Pragma("unroll") \
    for (int p = 0; p < 4; ++p) { \
        _Pragma("unroll") \
        for (int q = 0; q < 4; ++q) { \
            PKFMA_L(acc[2*p][q],   (fa)[p], (fb)[q]); \
            PKFMA_H(acc[2*p+1][q], (fa)[p], (fb)[q]); \
        } \
    } \
} while (0)

    LOADSTAGE(0);
    STORESTAGE(0);
    __syncthreads();
    int cur = 0;

    for (int k0 = 0; k0 < K; k0 += 16) {
        const bool more = (k0 + 16 < K);
        if (more) LOADSTAGE(k0 + 16);

        f32x2 fa0[4], fb0[4], fa1[4], fb1[4];
        RDFRAG(fa0, fb0, 0, cur);
        #pragma unroll
        for (int kk = 0; kk < 16; kk += 2) {
            RDFRAG(fa1, fb1, kk + 1, cur);
            FMAS(fa0, fb0);
            if (kk + 2 < 16) RDFRAG(fa0, fb0, kk + 2, cur);
            FMAS(fa1, fb1);
        }

        if (more) STORESTAGE(cur ^ 1);
        __syncthreads();
        cur ^= 1;
    }

    // rows: r<4 -> row0+tr4+r ; r>=4 -> row0+64+tr4+(r-4)
    #pragma unroll
    for (int r = 0; r < 8; ++r) {
        const int row = row0 + ((r < 4) ? (tr4 + r) : (64 + tr4 + r - 4));
        if (EPI == 0) {
            float4 lo4 = {acc[r][0].x, acc[r][0].y, acc[r][1].x, acc[r][1].y};
            float4 hi4 = {acc[r][2].x, acc[r][2].y, acc[r][3].x, acc[r][3].y};
            *(float4*)&Cf[(size_t)row * ldc + col0 + tc4]      = lo4;
            *(float4*)&Cf[(size_t)row * ldc + col0 + 64 + tc4] = hi4;
        } else {
            const float s = rvp[row];
            float v[8] = {acc[r][0].x, acc[r][0].y, acc[r][1].x, acc[r][1].y,
                          acc[r][2].x, acc[r][2].y, acc[r][3].x, acc[r][3].y};
            ushort4v o0, o1;
            #pragma unroll
            for (int j = 0; j < 4; ++j) {
                const float t0 = v[j];
                o0[j] = f2bf((t0 > 0.0f) ? s : ((t0 < 0.0f) ? -s : 0.0f));
                const float t1 = v[4 + j];
                o1[j] = f2bf((t1 > 0.0f) ? s : ((t1 < 0.0f) ? -s : 0.0f));
            }
            *(ushort4v*)&Cbp[(size_t)row * ldc + col0 + tc4]      = o0;
            *(ushort4v*)&Cbp[(size_t)row * ldc + col0 + 64 + tc4] = o1;
        }
    }
#undef LOADSTAGE
#undef STORESTAGE
#undef RDFRAG
#undef FMAS
}

// ---------------------------------------------------------------------------
// Quantize one key row (f32, numpy-exact decisions): nearest centroid
// (first-min ties), residual in place over Y, bf16 y_mse into Bbig[:,0:2048],
// sc = coef * ||res_group||  (continuous; vnorm applied in final colscale).
// ---------------------------------------------------------------------------
__global__ __launch_bounds__(256)
void quant_k(float* __restrict__ Y,
             unsigned short* __restrict__ Bmse,   // ld 4096
             const float* __restrict__ ch,
             const float* __restrict__ cl,
             float* __restrict__ sc_h,
             float* __restrict__ sc_l,
             double coefd)
{
#pragma clang fp contract(off)
    const int row = blockIdx.x;
    const int tid = threadIdx.x;
    const int c0 = tid * 8;
    const float h0 = ch[0], h1 = ch[1], h2 = ch[2], h3 = ch[3];
    const float l0 = cl[0], l1 = cl[1];

    float y[8], res[8];
    ushort8 cb;
    *(float4*)(y)     = *(const float4*)(Y + (size_t)row * 2048 + c0);
    *(float4*)(y + 4) = *(const float4*)(Y + (size_t)row * 2048 + c0 + 4);

    const bool high = (tid < 128);
    float ss = 0.0f;
    #pragma unroll
    for (int j = 0; j < 8; ++j) {
        const float v = y[j];
        float cbest;
        if (high) {
            cbest = h0;
            float bd = fabsf(v - h0), dd;
            dd = fabsf(v - h1); if (dd < bd) { bd = dd; cbest = h1; }
            dd = fabsf(v - h2); if (dd < bd) { bd = dd; cbest = h2; }
            dd = fabsf(v - h3); if (dd < bd) { bd = dd; cbest = h3; }
        } else {
            cbest = (fabsf(v - l1) < fabsf(v - l0)) ? l1 : l0;
        }
        res[j] = v - cbest;
        cb[j] = f2bf(cbest);
        ss += res[j] * res[j];
    }
    *(float4*)(Y + (size_t)row * 2048 + c0)     = *(float4*)(res);
    *(float4*)(Y + (size_t)row * 2048 + c0 + 4) = *(float4*)(res + 4);
    *(ushort8*)(Bmse + (size_t)row * 4096 + c0) = cb;

    __shared__ float sm[256];
    sm[tid] = ss;
    __syncthreads();
    for (int o = 64; o > 0; o >>= 1) {
        if ((tid & 127) < o) sm[tid] += sm[tid + o];
        __syncthreads();
    }
    if (tid == 0)   sc_h[row] = (float)(coefd * sqrt((double)sm[0]));
    if (tid == 128) sc_l[row] = (float)(coefd * sqrt((double)sm[128]));
}

// ---------------------------------------------------------------------------
// Continuous-path bf16 MFMA GEMM: C = A(MxK bf16) @ B(NxK bf16)^T, f32 accum.
// m97-pattern staging: __builtin_amdgcn_global_load_lds width=16 direct
// global->LDS (no VGPR round-trip, no ds_write), LINEAR unpadded [128][32]
// LDS (global_load_lds writes uniform-base + lane*16 -> layout must be
// linear; per-lane GLOBAL addr encodes the mapping). 2 barriers per K-step.
// 128x128 tile, 4 waves (2x2), 4x4 16x16x32 fragments per wave.
//   EPI 1: Cf[r,c] = acc * colscale[c]
//   EPI 2: Cb[r,c] = bf16(acc)
// C/D layout (m89-verified): row=(lane>>4)*4+reg, col=lane&15.
// ---------------------------------------------------------------------------
template <int EPI>
__global__ __launch_bounds__(256)
void gemm_mfma_k(const unsigned short* __restrict__ A, int lda, int a_zoff,
                 const unsigned short* __restrict__ B0,
                 const unsigned short* __restrict__ B1, int ldb,
                 float* __restrict__ Cf, unsigned short* __restrict__ Cb,
                 int c_zoff, int ldc, int K,
                 const float* __restrict__ colscale)
{
    __shared__ unsigned short As[128][32];
    __shared__ unsigned short Bs[128][32];

    const int z = blockIdx.z;
    const unsigned short* Ap = A + (size_t)z * a_zoff;
    const unsigned short* Bp = z ? B1 : B0;
    unsigned short* Cbp = (EPI == 2) ? (Cb + (size_t)z * c_zoff) : nullptr;

    const int tid = threadIdx.x;
    const int lane = tid & 63;
    const int w = tid >> 6;
    const int wm = w >> 1;
    const int wn = w & 1;
    const int row0 = blockIdx.y * 128;
    const int col0 = blockIdx.x * 128;
    const int frow = lane & 15;
    const int fk = (lane >> 4) * 8;

    // staging: wave w stages rows [w*32, w*32+32) of As and Bs via 2 calls
    // of 1KB each; lane l covers row base+(l>>2), elements (l&3)*8 .. +8.
    const int srow = lane >> 2;
    const int skel = (lane & 3) * 8;

    f32x4 acc[4][4] = {};

    for (int k0 = 0; k0 < K; k0 += 32) {
        __syncthreads();     // previous iteration's ds_reads complete
        #pragma unroll
        for (int c = 0; c < 2; ++c) {
            const int r = w * 32 + c * 16;
            const unsigned short* ga =
                Ap + (size_t)(row0 + r + srow) * lda + k0 + skel;
            const unsigned short* gb =
                Bp + (size_t)(col0 + r + srow) * ldb + k0 + skel;
            __builtin_amdgcn_global_load_lds(
                (const __attribute__((address_space(1))) void*)ga,
                (__attribute__((address_space(3))) void*)&As[r][0], 16, 0, 0);
            __builtin_amdgcn_global_load_lds(
                (const __attribute__((address_space(1))) void*)gb,
                (__attribute__((address_space(3))) void*)&Bs[r][0], 16, 0, 0);
        }
        __syncthreads();     // compiler drains vmcnt(0) before barrier

        bf16x8 af[4], bfr[4];
        #pragma unroll
        for (int mi = 0; mi < 4; ++mi)
            af[mi] = *(const bf16x8*)&As[wm * 64 + mi * 16 + frow][fk];
        #pragma unroll
        for (int ni = 0; ni < 4; ++ni)
            bfr[ni] = *(const bf16x8*)&Bs[wn * 64 + ni * 16 + frow][fk];
        #pragma unroll
        for (int mi = 0; mi < 4; ++mi)
            #pragma unroll
            for (int ni = 0; ni < 4; ++ni)
                acc[mi][ni] = __builtin_amdgcn_mfma_f32_16x16x32_bf16(
                    af[mi], bfr[ni], acc[mi][ni], 0, 0, 0);
    }

    const int drow = (lane >> 4) * 4;
    const int dcol = lane & 15;
    #pragma unroll
    for (int mi = 0; mi < 4; ++mi) {
        #pragma unroll
        for (int ni = 0; ni < 4; ++ni) {
            const int c = col0 + wn * 64 + ni * 16 + dcol;
            const float cs = (EPI == 1) ? colscale[c] : 0.0f;
            #pragma unroll
            for (int rg = 0; rg < 4; ++rg) {
                const int r = row0 + wm * 64 + mi * 16 + drow + rg;
                const float v = acc[mi][ni][rg];
                if (EPI == 1) Cf[(size_t)r * ldc + c] = v * cs;
                else          Cbp[(size_t)r * ldc + c] = f2bf(v);
            }
        }
    }
}

// ---------------------------------------------------------------------------
// Launch. Workspace (~120.1 MB):
//   kn    @   0M : 4096x2048 f32
//   Y     @  32M : 4096x2048 f32 (y, then residual in place)
//   Bbig  @  64M : 4096x4096 bf16  [ymse | sgn*sc_h | sgn*sc_l]
//   Abig  @  96M : 1024x4096 bf16  [q_rot | z_h | z_l]
//   Qb    @ 104M, Pib @ 108M, Sbh @ 116M, Sbl @ 118M : bf16 inputs
//   den   @ 120M, vnorm +16K, sc_h +32K, sc_l +48K
// ---------------------------------------------------------------------------
extern "C" void kernel_launch(void* const* d_in, const int* in_sizes, int n_in,
                              void* d_out, int out_size, void* d_ws, size_t ws_size,
                              hipStream_t stream)
{
    const float* queries = (const float*)d_in[0];
    const float* keys    = (const float*)d_in[1];
    const float* Pi      = (const float*)d_in[2];
    const float* ch      = (const float*)d_in[3];
    const float* cl      = (const float*)d_in[4];
    const float* S_high  = (const float*)d_in[5];
    const float* S_low   = (const float*)d_in[6];
    float* out = (float*)d_out;

    char* ws = (char*)d_ws;
    float*          kn    = (float*)(ws);
    float*          Y     = (float*)(ws + ((size_t)32 << 20));
    unsigned short* Bbig  = (unsigned short*)(ws + ((size_t)64 << 20));
    unsigned short* Abig  = (unsigned short*)(ws + ((size_t)96 << 20));
    unsigned short* Qb    = (unsigned short*)(ws + ((size_t)104 << 20));
    unsigned short* Pib   = (unsigned short*)(ws + ((size_t)108 << 20));
    unsigned short* Sbh   = (unsigned short*)(ws + ((size_t)116 << 20));
    unsigned short* Sbl   = (unsigned short*)(ws + ((size_t)118 << 20));
    float*          den   = (float*)(ws + ((size_t)120 << 20));
    float*          vnorm = (float*)(ws + ((size_t)120 << 20) + 16384);
    float*          sc_h  = (float*)(ws + ((size_t)120 << 20) + 32768);
    float*          sc_l  = (float*)(ws + ((size_t)120 << 20) + 49152);

    const double coefd = sqrt(M_PI / 2.0) / 1024.0;

    // numpy-exact norms
    norm_np_k<<<256, 256, 0, stream>>>(keys, den, vnorm);

    // decision-exact normalized keys
    kn_k<<<4096, 256, 0, stream>>>(keys, den, kn);

    // bf16 copies for the continuous MFMA path
    f2bf_k<<<1024, 256, 0, stream>>>(queries, Qb);
    f2bf_k<<<2048, 256, 0, stream>>>(Pi, Pib);
    f2bf_k<<<512, 256, 0, stream>>>(S_high, Sbh);
    f2bf_k<<<512, 256, 0, stream>>>(S_low, Sbl);

    // DECISION: Y = kn @ Pi^T  (f32 exact sequential chain, pk_fma, r11 cfg)
    gemm_dec_k<0><<<dim3(16, 32, 1), 256, 0, stream>>>(
        kn, 2048, 0, Pi, Pi, 2048, Y, nullptr, 0, 2048, 2048, nullptr, nullptr);

    // DECISION: quantize -> residual in Y, bf16 ymse in Bbig, sc_h/sc_l
    quant_k<<<4096, 256, 0, stream>>>(Y, Bbig, ch, cl, sc_h, sc_l, coefd);

    // DECISION: scaled signs (z=0: high, z=1: low) -> bf16 into Bbig cols 2048+
    gemm_dec_k<1><<<dim3(8, 32, 2), 256, 0, stream>>>(
        Y, 2048, 1024, S_high, S_low, 1024,
        nullptr, Bbig + 2048, 1024, 4096, 1024, sc_h, sc_l);

    // CONTINUOUS (bf16 MFMA, global_load_lds staging): Abig = [q_rot | z_h | z_l]
    gemm_mfma_k<2><<<dim3(16, 8, 1), 256, 0, stream>>>(
        Qb, 2048, 0, Pib, Pib, 2048, nullptr, Abig, 0, 4096, 2048, nullptr);
    gemm_mfma_k<2><<<dim3(8, 8, 2), 256, 0, stream>>>(
        Abig, 4096, 1024, Sbh, Sbl, 1024, nullptr, Abig + 2048, 1024, 4096, 1024, nullptr);

    // CONTINUOUS: out = (Abig @ Bbig^T) * vnorm[col]   (K=4096 fused)
    gemm_mfma_k<1><<<dim3(32, 8, 1), 256, 0, stream>>>(
        Abig, 4096, 0, Bbig, Bbig, 4096, out, nullptr, 0, 4096, 4096, vnorm);
}